// Round 11
// baseline (2788.018 us; speedup 1.0000x reference)
//
#include <hip/hip_runtime.h>

#define O_N 100000
#define R_N 1000000
#define DIM 128
#define SD 384
#define HD 256
#define BR 64
#define NT (R_N / BR)
#define OBJ8 (O_N * DIM / 8)

typedef __attribute__((ext_vector_type(8))) short short8;
typedef __attribute__((ext_vector_type(4))) float f32x4;

static __device__ __forceinline__ unsigned short f2bf(float x) {
    union { float f; unsigned int u; } v; v.f = x;
    unsigned int r = v.u + 0x7FFFu + ((v.u >> 16) & 1u);
    return (unsigned short)(r >> 16);
}
static __device__ __forceinline__ unsigned long long pack4(f32x4 v) {
    return  (unsigned long long)f2bf(v.x)
         | ((unsigned long long)f2bf(v.y) << 16)
         | ((unsigned long long)f2bf(v.z) << 32)
         | ((unsigned long long)f2bf(v.w) << 48);
}

// ---- K0: transpose + convert weights to bf16 ----------------------------
__global__ void prep_weights(const float* __restrict__ W1, const float* __restrict__ W2,
                             unsigned short* __restrict__ W1T, unsigned short* __restrict__ W2T) {
    int i = blockIdx.x * 256 + threadIdx.x;
    if (i < SD * HD) {
        int h = i / SD, k = i - h * SD;
        W1T[i] = f2bf(W1[k * HD + h]);
    } else {
        int j = i - SD * HD;
        int c = j / HD, k = j - c * HD;
        W2T[j] = f2bf(W2[k * SD + c]);
    }
}

// ---- K1: pre-convert object_feats to bf16 (rel read f32 in main kernel) --
__global__ void conv_obj(const float* __restrict__ objF, unsigned short* __restrict__ objBF) {
    int i = blockIdx.x * 256 + threadIdx.x;
    if (i < OBJ8) {
        f32x4 v0 = ((const f32x4*)(objF + (size_t)i * 8))[0];
        f32x4 v1 = ((const f32x4*)(objF + (size_t)i * 8))[1];
        unsigned long long* dd = (unsigned long long*)(objBF + (size_t)i * 8);
        dd[0] = pack4(v0);
        dd[1] = pack4(v1);
    }
}

// ---- K2: triplet copy (as float) + degree counts ------------------------
__global__ void trip_cnt(const int* __restrict__ trip, float* __restrict__ tripOut,
                         float* __restrict__ lenOut, float* __restrict__ cnt,
                         const int* __restrict__ tlen) {
    int i = blockIdx.x * 256 + threadIdx.x;
    if (i < R_N) {
        int s = trip[3 * i], o = trip[3 * i + 1], t2 = trip[3 * i + 2];
        tripOut[3 * i]     = (float)s;
        tripOut[3 * i + 1] = (float)o;
        tripOut[3 * i + 2] = (float)t2;
        atomicAdd(&cnt[min(max(s, 0), O_N - 1)], 1.0f);
        atomicAdd(&cnt[min(max(o, 0), O_N - 1)], 1.0f);
        if (i == 0) lenOut[0] = (float)tlen[0];
    }
}

// ---- K3: fused MLP, NO fill phase ----------------------------------------
// Round-11: GEMM1 B-fragments loaded DIRECTLY from global (objBF bf16 for
// sub/obj regions; relF f32 + in-register cvt for rel region). No Xs LDS, no
// global_load_lds, no fill barriers. Only Hs (cross-wave h-exchange) + ONE
// __syncthreads remain. GEMM2 + epilogue identical to round 7.
__global__ void mlp_kernel(const unsigned short* __restrict__ objBF, const float* __restrict__ relF,
                           const unsigned short* __restrict__ W1T, const unsigned short* __restrict__ W2T,
                           const float* __restrict__ b1, const float* __restrict__ b2,
                           const int* __restrict__ trip,
                           float* __restrict__ accB, float* __restrict__ relOut) {
    __shared__ __align__(16) unsigned char Hs[32768];   // H[64][256] bf16, XOR-swizzled
    __shared__ int idxBuf[128];                          // [0..63]=sub, [64..127]=obj

    const int tid  = threadIdx.x;
    const int lane = tid & 63;
    const int w    = tid >> 6;
    const int r0   = blockIdx.x * BR;
    const int l15  = lane & 15;
    const int l4   = lane >> 4;
    const int hW   = w * 64;
    const int cW   = w * 96;

    // per-lane gather indices for GEMM1: row = nr*16 + l15
    int subG[4], objG[4];
    #pragma unroll
    for (int nr = 0; nr < 4; ++nr) {
        int rr = r0 + nr * 16 + l15;
        subG[nr] = min(max(trip[3 * rr], 0), O_N - 1);
        objG[nr] = min(max(trip[3 * rr + 1], 0), O_N - 1);
    }

    // ---- GEMM1 (swapped): D1[h][rel] = W1T(A) * X^T(B), frags from global
    f32x4 acc1[4][4];
    #pragma unroll
    for (int a = 0; a < 4; ++a)
        #pragma unroll
        for (int b = 0; b < 4; ++b) acc1[a][b] = (f32x4)0.0f;

    #define G1STEP(K0, BFR_EXPR)                                              \
    {                                                                         \
        const int k0 = (K0);                                                  \
        short8 af[4], bfr[4];                                                 \
        _Pragma("unroll")                                                     \
        for (int nr = 0; nr < 4; ++nr) { BFR_EXPR; }                          \
        _Pragma("unroll")                                                     \
        for (int mh = 0; mh < 4; ++mh)                                        \
            af[mh] = *(const short8*)(W1T + (hW + mh * 16 + l15) * SD + k0 + 8 * l4); \
        _Pragma("unroll")                                                     \
        for (int mh = 0; mh < 4; ++mh)                                        \
            _Pragma("unroll")                                                 \
            for (int nr = 0; nr < 4; ++nr)                                    \
                acc1[mh][nr] = __builtin_amdgcn_mfma_f32_16x16x32_bf16(       \
                    af[mh], bfr[nr], acc1[mh][nr], 0, 0, 0);                  \
    }

    // sub region: k = 0..127 from objBF[subG]
    #pragma unroll
    for (int ks = 0; ks < 4; ++ks)
        G1STEP(ks * 32,
            bfr[nr] = *(const short8*)(objBF + (size_t)subG[nr] * DIM + k0 + l4 * 8));
    // rel region: k = 128..255 from relF (f32 -> bf16 in-register)
    #pragma unroll
    for (int ks = 4; ks < 8; ++ks)
        G1STEP(ks * 32,
            {
                const float* rp = relF + (size_t)(r0 + nr * 16 + l15) * DIM + (k0 - 128) + l4 * 8;
                f32x4 a0 = ((const f32x4*)rp)[0];
                f32x4 a1 = ((const f32x4*)rp)[1];
                union { unsigned long long q[2]; short8 v; } u;
                u.q[0] = pack4(a0); u.q[1] = pack4(a1);
                bfr[nr] = u.v;
            });
    // obj region: k = 256..383 from objBF[objG]
    #pragma unroll
    for (int ks = 8; ks < 12; ++ks)
        G1STEP(ks * 32,
            bfr[nr] = *(const short8*)(objBF + (size_t)objG[nr] * DIM + (k0 - 256) + l4 * 8));
    #undef G1STEP

    // ---- bias + relu + pack -> Hs; stage epilogue idx --------------------
    #pragma unroll
    for (int mh = 0; mh < 4; ++mh) {
        int hbase = hW + mh * 16 + 4 * l4;
        float bb0 = b1[hbase], bb1 = b1[hbase + 1], bb2 = b1[hbase + 2], bb3 = b1[hbase + 3];
        int hb   = hbase >> 3;
        int half = (hbase >> 2) & 1;
        #pragma unroll
        for (int nr = 0; nr < 4; ++nr) {
            int rel = nr * 16 + l15;
            unsigned long long pk =
                  (unsigned long long)f2bf(fmaxf(acc1[mh][nr][0] + bb0, 0.f))
                | ((unsigned long long)f2bf(fmaxf(acc1[mh][nr][1] + bb1, 0.f)) << 16)
                | ((unsigned long long)f2bf(fmaxf(acc1[mh][nr][2] + bb2, 0.f)) << 32)
                | ((unsigned long long)f2bf(fmaxf(acc1[mh][nr][3] + bb3, 0.f)) << 48);
            *(unsigned long long*)(Hs + rel * 512 + ((hb ^ (rel & 15)) << 4) + half * 8) = pk;
        }
    }
    if (tid < 2 * BR) {
        int rr = r0 + (tid & (BR - 1));
        idxBuf[tid] = min(max(trip[3 * rr + (tid >> 6)], 0), O_N - 1);
    }
    __syncthreads();   // the ONLY barrier: Hs + idxBuf visible

    // ---- GEMM2: D2[rel][c] = H(A) * W2T(B) ------------------------------
    f32x4 acc2[4][6];
    #pragma unroll
    for (int a = 0; a < 4; ++a)
        #pragma unroll
        for (int b = 0; b < 6; ++b) acc2[a][b] = (f32x4)0.0f;

    #pragma unroll
    for (int ks = 0; ks < 8; ++ks) {
        int k0 = ks * 32;
        short8 ha[4], wb[6];
        #pragma unroll
        for (int ma = 0; ma < 4; ++ma) {
            int rel = ma * 16 + l15;
            int hb  = (k0 >> 3) + l4;
            ha[ma] = *(const short8*)(Hs + rel * 512 + ((hb ^ (rel & 15)) << 4));
        }
        #pragma unroll
        for (int nb = 0; nb < 6; ++nb) {
            int c = cW + nb * 16 + l15;
            wb[nb] = *(const short8*)(W2T + c * HD + k0 + 8 * l4);
        }
        #pragma unroll
        for (int ma = 0; ma < 4; ++ma)
            #pragma unroll
            for (int nb = 0; nb < 6; ++nb)
                acc2[ma][nb] = __builtin_amdgcn_mfma_f32_16x16x32_bf16(
                    ha[ma], wb[nb], acc2[ma][nb], 0, 0, 0);
    }

    // ---- epilogue: bias + region-split store / f32 scatter-add ----------
    #pragma unroll
    for (int ma = 0; ma < 4; ++ma) {
        int rloc = ma * 16 + 4 * l4;
        int rg   = r0 + rloc;
        int subs[4], objs[4];
        #pragma unroll
        for (int q = 0; q < 4; ++q) {
            subs[q] = idxBuf[rloc + q];
            objs[q] = idxBuf[BR + rloc + q];
        }
        #pragma unroll
        for (int nb = 0; nb < 6; ++nb) {
            int c = cW + nb * 16 + l15;
            float b2v = b2[c];
            #pragma unroll
            for (int q = 0; q < 4; ++q) {
                float v = acc2[ma][nb][q] + b2v;
                if (c < DIM) {
                    atomicAdd(accB + (size_t)subs[q] * DIM + c, v);
                } else if (c < 2 * DIM) {
                    relOut[(size_t)(rg + q) * DIM + (c - DIM)] = v;
                } else {
                    atomicAdd(accB + (size_t)objs[q] * DIM + (c - 2 * DIM), v);
                }
            }
        }
    }
}

// ---- K4: output_feat = acc / max(cnt,1) + object_feats -------------------
__global__ void finalize(const float* __restrict__ accB, const float* __restrict__ cnt,
                         const float* __restrict__ objF, float* __restrict__ outF) {
    int i = blockIdx.x * 256 + threadIdx.x;
    if (i < O_N * DIM / 4) {
        int row = i >> 5;
        float c = fmaxf(cnt[row], 1.0f);
        f32x4 a = ((const f32x4*)accB)[i];
        f32x4 o = ((const f32x4*)objF)[i];
        f32x4 r;
        r.x = a.x / c + o.x;
        r.y = a.y / c + o.y;
        r.z = a.z / c + o.z;
        r.w = a.w / c + o.w;
        ((f32x4*)outF)[i] = r;
    }
}

extern "C" void kernel_launch(void* const* d_in, const int* in_sizes, int n_in,
                              void* d_out, int out_size, void* d_ws, size_t ws_size,
                              hipStream_t stream) {
    const float* objF = (const float*)d_in[0];
    const float* relF = (const float*)d_in[1];
    const float* W1   = (const float*)d_in[2];
    const float* b1   = (const float*)d_in[3];
    const float* W2   = (const float*)d_in[4];
    const float* b2   = (const float*)d_in[5];
    const int*   trip = (const int*)d_in[6];
    const int*   tlen = (const int*)d_in[7];

    float* outF    = (float*)d_out;
    float* relOut  = outF + (size_t)O_N * DIM;
    float* tripOut = relOut + (size_t)R_N * DIM;
    float* lenOut  = tripOut + (size_t)R_N * 3;

    // ws layout (~78 MB): W1T | W2T | accB | cnt | objBF
    unsigned short* W1T = (unsigned short*)d_ws;
    unsigned short* W2T = W1T + SD * HD;
    float* accB = (float*)(W2T + SD * HD);
    float* cnt  = accB + (size_t)O_N * DIM;
    unsigned short* objBF = (unsigned short*)(cnt + O_N);

    (void)hipMemsetAsync(accB, 0, ((size_t)O_N * DIM + O_N) * sizeof(float), stream);
    prep_weights<<<(2 * SD * HD) / 256, 256, 0, stream>>>(W1, W2, W1T, W2T);
    conv_obj<<<(OBJ8 + 255) / 256, 256, 0, stream>>>(objF, objBF);
    trip_cnt<<<(R_N + 255) / 256, 256, 0, stream>>>(trip, tripOut, lenOut, cnt, tlen);
    mlp_kernel<<<NT, 256, 0, stream>>>(objBF, relF, W1T, W2T, b1, b2, trip, accB, relOut);
    finalize<<<(O_N * DIM / 4 + 255) / 256, 256, 0, stream>>>(accB, cnt, objF, outF);
}

// Round 12
// 1620.405 us; speedup vs baseline: 1.7206x; 1.7206x over previous
//
#include <hip/hip_runtime.h>

#define O_N 100000
#define R_N 1000000
#define DIM 128
#define SD 384
#define HD 256
#define BR 64
#define NT (R_N / BR)
#define OBJ8 (O_N * DIM / 8)

typedef __attribute__((ext_vector_type(8))) short short8;
typedef __attribute__((ext_vector_type(4))) float f32x4;

static __device__ __forceinline__ unsigned short f2bf(float x) {
    union { float f; unsigned int u; } v; v.f = x;
    unsigned int r = v.u + 0x7FFFu + ((v.u >> 16) & 1u);
    return (unsigned short)(r >> 16);
}
static __device__ __forceinline__ unsigned long long pack4(f32x4 v) {
    return  (unsigned long long)f2bf(v.x)
         | ((unsigned long long)f2bf(v.y) << 16)
         | ((unsigned long long)f2bf(v.z) << 32)
         | ((unsigned long long)f2bf(v.w) << 48);
}

// ---- K0: transpose + convert weights to bf16 ----------------------------
__global__ void prep_weights(const float* __restrict__ W1, const float* __restrict__ W2,
                             unsigned short* __restrict__ W1T, unsigned short* __restrict__ W2T) {
    int i = blockIdx.x * 256 + threadIdx.x;
    if (i < SD * HD) {
        int h = i / SD, k = i - h * SD;
        W1T[i] = f2bf(W1[k * HD + h]);
    } else {
        int j = i - SD * HD;
        int c = j / HD, k = j - c * HD;
        W2T[j] = f2bf(W2[k * SD + c]);
    }
}

// ---- K1: pre-convert object_feats to bf16 (rel read f32 in main kernel) --
__global__ void conv_obj(const float* __restrict__ objF, unsigned short* __restrict__ objBF) {
    int i = blockIdx.x * 256 + threadIdx.x;
    if (i < OBJ8) {
        f32x4 v0 = ((const f32x4*)(objF + (size_t)i * 8))[0];
        f32x4 v1 = ((const f32x4*)(objF + (size_t)i * 8))[1];
        unsigned long long* dd = (unsigned long long*)(objBF + (size_t)i * 8);
        dd[0] = pack4(v0);
        dd[1] = pack4(v1);
    }
}

// ---- K2: triplet copy (as float) + degree counts ------------------------
__global__ void trip_cnt(const int* __restrict__ trip, float* __restrict__ tripOut,
                         float* __restrict__ lenOut, float* __restrict__ cnt,
                         const int* __restrict__ tlen) {
    int i = blockIdx.x * 256 + threadIdx.x;
    if (i < R_N) {
        int s = trip[3 * i], o = trip[3 * i + 1], t2 = trip[3 * i + 2];
        tripOut[3 * i]     = (float)s;
        tripOut[3 * i + 1] = (float)o;
        tripOut[3 * i + 2] = (float)t2;
        atomicAdd(&cnt[min(max(s, 0), O_N - 1)], 1.0f);
        atomicAdd(&cnt[min(max(o, 0), O_N - 1)], 1.0f);
        if (i == 0) lenOut[0] = (float)tlen[0];
    }
}

// ---- K3: fused MLP, NO fill phase, VGPR-budgeted -------------------------
// Round-12 = round-11 with __launch_bounds__(256,3): VGPR cap 170 covers the
// ~160-reg peak (acc2 + fragments + addressing) -> no spill. Round 11's
// missing bound let the compiler pick 64 VGPR and spill 3.4 GB to scratch.
__global__ __launch_bounds__(256, 3)
void mlp_kernel(const unsigned short* __restrict__ objBF, const float* __restrict__ relF,
                const unsigned short* __restrict__ W1T, const unsigned short* __restrict__ W2T,
                const float* __restrict__ b1, const float* __restrict__ b2,
                const int* __restrict__ trip,
                float* __restrict__ accB, float* __restrict__ relOut) {
    __shared__ __align__(16) unsigned char Hs[32768];   // H[64][256] bf16, XOR-swizzled
    __shared__ int idxBuf[128];                          // [0..63]=sub, [64..127]=obj

    const int tid  = threadIdx.x;
    const int lane = tid & 63;
    const int w    = tid >> 6;
    const int r0   = blockIdx.x * BR;
    const int l15  = lane & 15;
    const int l4   = lane >> 4;
    const int hW   = w * 64;
    const int cW   = w * 96;

    // per-lane gather indices for GEMM1: row = nr*16 + l15
    int subG[4], objG[4];
    #pragma unroll
    for (int nr = 0; nr < 4; ++nr) {
        int rr = r0 + nr * 16 + l15;
        subG[nr] = min(max(trip[3 * rr], 0), O_N - 1);
        objG[nr] = min(max(trip[3 * rr + 1], 0), O_N - 1);
    }

    // ---- GEMM1 (swapped): D1[h][rel] = W1T(A) * X^T(B), frags from global
    f32x4 acc1[4][4];
    #pragma unroll
    for (int a = 0; a < 4; ++a)
        #pragma unroll
        for (int b = 0; b < 4; ++b) acc1[a][b] = (f32x4)0.0f;

    #define G1STEP(K0, BFR_EXPR)                                              \
    {                                                                         \
        const int k0 = (K0);                                                  \
        short8 af[4], bfr[4];                                                 \
        _Pragma("unroll")                                                     \
        for (int nr = 0; nr < 4; ++nr) { BFR_EXPR; }                          \
        _Pragma("unroll")                                                     \
        for (int mh = 0; mh < 4; ++mh)                                        \
            af[mh] = *(const short8*)(W1T + (hW + mh * 16 + l15) * SD + k0 + 8 * l4); \
        _Pragma("unroll")                                                     \
        for (int mh = 0; mh < 4; ++mh)                                        \
            _Pragma("unroll")                                                 \
            for (int nr = 0; nr < 4; ++nr)                                    \
                acc1[mh][nr] = __builtin_amdgcn_mfma_f32_16x16x32_bf16(       \
                    af[mh], bfr[nr], acc1[mh][nr], 0, 0, 0);                  \
    }

    // sub region: k = 0..127 from objBF[subG]
    #pragma unroll
    for (int ks = 0; ks < 4; ++ks)
        G1STEP(ks * 32,
            bfr[nr] = *(const short8*)(objBF + (size_t)subG[nr] * DIM + k0 + l4 * 8));
    // rel region: k = 128..255 from relF (f32 -> bf16 in-register)
    #pragma unroll
    for (int ks = 4; ks < 8; ++ks)
        G1STEP(ks * 32,
            {
                const float* rp = relF + (size_t)(r0 + nr * 16 + l15) * DIM + (k0 - 128) + l4 * 8;
                f32x4 a0 = ((const f32x4*)rp)[0];
                f32x4 a1 = ((const f32x4*)rp)[1];
                union { unsigned long long q[2]; short8 v; } u;
                u.q[0] = pack4(a0); u.q[1] = pack4(a1);
                bfr[nr] = u.v;
            });
    // obj region: k = 256..383 from objBF[objG]
    #pragma unroll
    for (int ks = 8; ks < 12; ++ks)
        G1STEP(ks * 32,
            bfr[nr] = *(const short8*)(objBF + (size_t)objG[nr] * DIM + (k0 - 256) + l4 * 8));
    #undef G1STEP

    // ---- bias + relu + pack -> Hs; stage epilogue idx --------------------
    #pragma unroll
    for (int mh = 0; mh < 4; ++mh) {
        int hbase = hW + mh * 16 + 4 * l4;
        float bb0 = b1[hbase], bb1 = b1[hbase + 1], bb2 = b1[hbase + 2], bb3 = b1[hbase + 3];
        int hb   = hbase >> 3;
        int half = (hbase >> 2) & 1;
        #pragma unroll
        for (int nr = 0; nr < 4; ++nr) {
            int rel = nr * 16 + l15;
            unsigned long long pk =
                  (unsigned long long)f2bf(fmaxf(acc1[mh][nr][0] + bb0, 0.f))
                | ((unsigned long long)f2bf(fmaxf(acc1[mh][nr][1] + bb1, 0.f)) << 16)
                | ((unsigned long long)f2bf(fmaxf(acc1[mh][nr][2] + bb2, 0.f)) << 32)
                | ((unsigned long long)f2bf(fmaxf(acc1[mh][nr][3] + bb3, 0.f)) << 48);
            *(unsigned long long*)(Hs + rel * 512 + ((hb ^ (rel & 15)) << 4) + half * 8) = pk;
        }
    }
    if (tid < 2 * BR) {
        int rr = r0 + (tid & (BR - 1));
        idxBuf[tid] = min(max(trip[3 * rr + (tid >> 6)], 0), O_N - 1);
    }
    __syncthreads();   // the ONLY barrier: Hs + idxBuf visible

    // ---- GEMM2: D2[rel][c] = H(A) * W2T(B) ------------------------------
    f32x4 acc2[4][6];
    #pragma unroll
    for (int a = 0; a < 4; ++a)
        #pragma unroll
        for (int b = 0; b < 6; ++b) acc2[a][b] = (f32x4)0.0f;

    #pragma unroll
    for (int ks = 0; ks < 8; ++ks) {
        int k0 = ks * 32;
        short8 ha[4], wb[6];
        #pragma unroll
        for (int ma = 0; ma < 4; ++ma) {
            int rel = ma * 16 + l15;
            int hb  = (k0 >> 3) + l4;
            ha[ma] = *(const short8*)(Hs + rel * 512 + ((hb ^ (rel & 15)) << 4));
        }
        #pragma unroll
        for (int nb = 0; nb < 6; ++nb) {
            int c = cW + nb * 16 + l15;
            wb[nb] = *(const short8*)(W2T + c * HD + k0 + 8 * l4);
        }
        #pragma unroll
        for (int ma = 0; ma < 4; ++ma)
            #pragma unroll
            for (int nb = 0; nb < 6; ++nb)
                acc2[ma][nb] = __builtin_amdgcn_mfma_f32_16x16x32_bf16(
                    ha[ma], wb[nb], acc2[ma][nb], 0, 0, 0);
    }

    // ---- epilogue: bias + region-split store / f32 scatter-add ----------
    #pragma unroll
    for (int ma = 0; ma < 4; ++ma) {
        int rloc = ma * 16 + 4 * l4;
        int rg   = r0 + rloc;
        int subs[4], objs[4];
        #pragma unroll
        for (int q = 0; q < 4; ++q) {
            subs[q] = idxBuf[rloc + q];
            objs[q] = idxBuf[BR + rloc + q];
        }
        #pragma unroll
        for (int nb = 0; nb < 6; ++nb) {
            int c = cW + nb * 16 + l15;
            float b2v = b2[c];
            #pragma unroll
            for (int q = 0; q < 4; ++q) {
                float v = acc2[ma][nb][q] + b2v;
                if (c < DIM) {
                    atomicAdd(accB + (size_t)subs[q] * DIM + c, v);
                } else if (c < 2 * DIM) {
                    relOut[(size_t)(rg + q) * DIM + (c - DIM)] = v;
                } else {
                    atomicAdd(accB + (size_t)objs[q] * DIM + (c - 2 * DIM), v);
                }
            }
        }
    }
}

// ---- K4: output_feat = acc / max(cnt,1) + object_feats -------------------
__global__ void finalize(const float* __restrict__ accB, const float* __restrict__ cnt,
                         const float* __restrict__ objF, float* __restrict__ outF) {
    int i = blockIdx.x * 256 + threadIdx.x;
    if (i < O_N * DIM / 4) {
        int row = i >> 5;
        float c = fmaxf(cnt[row], 1.0f);
        f32x4 a = ((const f32x4*)accB)[i];
        f32x4 o = ((const f32x4*)objF)[i];
        f32x4 r;
        r.x = a.x / c + o.x;
        r.y = a.y / c + o.y;
        r.z = a.z / c + o.z;
        r.w = a.w / c + o.w;
        ((f32x4*)outF)[i] = r;
    }
}

extern "C" void kernel_launch(void* const* d_in, const int* in_sizes, int n_in,
                              void* d_out, int out_size, void* d_ws, size_t ws_size,
                              hipStream_t stream) {
    const float* objF = (const float*)d_in[0];
    const float* relF = (const float*)d_in[1];
    const float* W1   = (const float*)d_in[2];
    const float* b1   = (const float*)d_in[3];
    const float* W2   = (const float*)d_in[4];
    const float* b2   = (const float*)d_in[5];
    const int*   trip = (const int*)d_in[6];
    const int*   tlen = (const int*)d_in[7];

    float* outF    = (float*)d_out;
    float* relOut  = outF + (size_t)O_N * DIM;
    float* tripOut = relOut + (size_t)R_N * DIM;
    float* lenOut  = tripOut + (size_t)R_N * 3;

    // ws layout (~78 MB): W1T | W2T | accB | cnt | objBF
    unsigned short* W1T = (unsigned short*)d_ws;
    unsigned short* W2T = W1T + SD * HD;
    float* accB = (float*)(W2T + SD * HD);
    float* cnt  = accB + (size_t)O_N * DIM;
    unsigned short* objBF = (unsigned short*)(cnt + O_N);

    (void)hipMemsetAsync(accB, 0, ((size_t)O_N * DIM + O_N) * sizeof(float), stream);
    prep_weights<<<(2 * SD * HD) / 256, 256, 0, stream>>>(W1, W2, W1T, W2T);
    conv_obj<<<(OBJ8 + 255) / 256, 256, 0, stream>>>(objF, objBF);
    trip_cnt<<<(R_N + 255) / 256, 256, 0, stream>>>(trip, tripOut, lenOut, cnt, tlen);
    mlp_kernel<<<NT, 256, 0, stream>>>(objBF, relF, W1T, W2T, b1, b2, trip, accB, relOut);
    finalize<<<(O_N * DIM / 4 + 255) / 256, 256, 0, stream>>>(accB, cnt, objF, outF);
}